// Round 1
// baseline (449.271 us; speedup 1.0000x reference)
//
#include <hip/hip_runtime.h>
#include <stdint.h>

#define M_CH       384
#define TR         15
#define MARGIN     20
#define CHUNK_ROWS 16
#define BM_WORDS   192        // words per chunk = 16*384/32
#define WPR        12         // words per row = 384/32
#define WIN_ROWS   46         // CHUNK_ROWS + 2*TR

// spread 8 bits of x to positions 0,4,8,...,28
__device__ __forceinline__ uint32_t spread4(uint32_t x) {
    x = (x | (x << 12)) & 0x000F000Fu;
    x = (x | (x << 6))  & 0x03030303u;
    x = (x | (x << 3))  & 0x11111111u;
    return x;
}

// ---------------- K1: streaming threshold pass (+ neighbor masks in the
// last block, folded in to drop a serialized launch) ----------------
// Wave handles 256 contiguous float4s (1024 samples = 32 words):
// 4 coalesced 1-KB loads in flight, 16 ballots, lanes 0-31 store 32
// contiguous words (128-B coalesced store). No margin here (competitors
// outside margin must keep their bits).
__global__ __launch_bounds__(256)
void cand_kernel(const float* __restrict__ traces,
                 const float* __restrict__ locs,
                 long n4, long nwords, int nbrBlock,
                 uint32_t* __restrict__ candWords,
                 uint32_t* __restrict__ nEntries,
                 uint8_t* __restrict__ entryWord,
                 uint32_t* __restrict__ entryMask) {
    if ((int)blockIdx.x >= nbrBlock) {
        // ---- neighbor-mask role (one block) ----
        __shared__ float lx[M_CH], ly[M_CH];
        const int t = threadIdx.x;
        for (int c = t; c < M_CH; c += 256) {
            lx[c] = locs[2 * c];
            ly[c] = locs[2 * c + 1];
        }
        __syncthreads();
        for (int c0 = t; c0 < M_CH; c0 += 256) {
            float x = lx[c0], y = ly[c0];
            int ne = 0;
            for (int k = 0; k < WPR; ++k) {
                uint32_t mk = 0;
                #pragma unroll
                for (int b = 0; b < 32; ++b) {
                    int c = k * 32 + b;
                    float dx = x - lx[c], dy = y - ly[c];
                    if (sqrtf(dx * dx + dy * dy) <= 100.0f) mk |= 1u << b;
                }
                if (mk) {
                    entryWord[c0 * WPR + ne] = (uint8_t)k;
                    entryMask[c0 * WPR + ne] = mk;
                    ne++;
                }
            }
            nEntries[c0] = (uint32_t)ne;
        }
        return;
    }

    const int lane = threadIdx.x & 63;
    const long wv = (((long)blockIdx.x * 256) + threadIdx.x) >> 6;
    const long fb = wv * 256;                  // first float4 of this wave
    uint64_t B00,B01,B02,B03, B10,B11,B12,B13,
             B20,B21,B22,B23, B30,B31,B32,B33;
    {
        float4 v0 = make_float4(0,0,0,0), v1 = v0, v2 = v0, v3 = v0;
        long i0 = fb + 0 * 64 + lane;
        long i1 = fb + 1 * 64 + lane;
        long i2 = fb + 2 * 64 + lane;
        long i3 = fb + 3 * 64 + lane;
        if (i0 < n4) v0 = ((const float4*)traces)[i0];
        if (i1 < n4) v1 = ((const float4*)traces)[i1];
        if (i2 < n4) v2 = ((const float4*)traces)[i2];
        if (i3 < n4) v3 = ((const float4*)traces)[i3];
        B00 = __ballot(v0.x <= -3.0f); B01 = __ballot(v0.y <= -3.0f);
        B02 = __ballot(v0.z <= -3.0f); B03 = __ballot(v0.w <= -3.0f);
        B10 = __ballot(v1.x <= -3.0f); B11 = __ballot(v1.y <= -3.0f);
        B12 = __ballot(v1.z <= -3.0f); B13 = __ballot(v1.w <= -3.0f);
        B20 = __ballot(v2.x <= -3.0f); B21 = __ballot(v2.y <= -3.0f);
        B22 = __ballot(v2.z <= -3.0f); B23 = __ballot(v2.w <= -3.0f);
        B30 = __ballot(v3.x <= -3.0f); B31 = __ballot(v3.y <= -3.0f);
        B32 = __ballot(v3.z <= -3.0f); B33 = __ballot(v3.w <= -3.0f);
    }
    if (lane < 32) {
        int k  = lane >> 3;           // which load group
        int sh = (lane & 7) * 8;      // which byte of the ballot
        uint64_t b0 = (k & 2) ? ((k & 1) ? B30 : B20) : ((k & 1) ? B10 : B00);
        uint64_t b1 = (k & 2) ? ((k & 1) ? B31 : B21) : ((k & 1) ? B11 : B01);
        uint64_t b2 = (k & 2) ? ((k & 1) ? B32 : B22) : ((k & 1) ? B12 : B02);
        uint64_t b3 = (k & 2) ? ((k & 1) ? B33 : B23) : ((k & 1) ? B13 : B03);
        uint32_t w = spread4((uint32_t)(b0 >> sh) & 0xFFu)
                   | (spread4((uint32_t)(b1 >> sh) & 0xFFu) << 1)
                   | (spread4((uint32_t)(b2 >> sh) & 0xFFu) << 2)
                   | (spread4((uint32_t)(b3 >> sh) & 0xFFu) << 3);
        long wIdx = wv * 32 + lane;
        if (wIdx < nwords) candWords[wIdx] = w;
    }
}

// ---------------- K2: validate via LDS-staged window + per-chunk count ----
// Block = 192 threads = one 16-row chunk. The whole competitor window
// (rows r0-15 .. r0+30, all 12 words/row = 552 words) is CONTIGUOUS in
// candWords -> stage it into LDS once (coalesced). Fast path: per
// candidate/entry a 31-word OR from LDS (self bit masked at dt=TR); if
// zero, valid with ZERO global loads. Slow path (rare) re-derives the
// hit rows from LDS and compares trace values only on actual hits.
__global__ __launch_bounds__(192)
void validate_count_kernel(const float* __restrict__ traces, int N, long nwords,
                           const uint32_t* __restrict__ nEntries,
                           const uint8_t* __restrict__ entryWord,
                           const uint32_t* __restrict__ entryMask,
                           const uint32_t* __restrict__ candWords,
                           uint32_t* __restrict__ validOut,
                           uint32_t* __restrict__ chunkCounts) {
    __shared__ uint32_t win[WIN_ROWS * WPR];   // 552 words = 2.2 KB
    __shared__ uint32_t red[3];
    const int t = threadIdx.x;
    const int r0 = (int)blockIdx.x * CHUNK_ROWS;

    {
        const long base = (long)(r0 - TR) * WPR;
        #pragma unroll
        for (int i0 = 0; i0 < WIN_ROWS * WPR; i0 += 192) {
            int i = i0 + t;
            if (i < WIN_ROWS * WPR) {
                long g = base + i;
                win[i] = (g >= 0 && g < nwords) ? candWords[g] : 0u;
            }
        }
    }
    __syncthreads();

    const int lr = t / WPR;        // local row 0..15
    const int wi = t - lr * WPR;   // word-in-row 0..11
    const int r  = r0 + lr;
    const long w = (long)blockIdx.x * BM_WORDS + t;

    uint32_t out = 0;
    if (w < nwords) {
        uint32_t word = win[(lr + TR) * WPR + wi];
        if (word && r >= MARGIN && r < N - MARGIN) {
            out = word;
            uint32_t tmp = word;
            while (tmp) {
                int bit = __ffs(tmp) - 1;
                tmp &= tmp - 1;
                const int c = wi * 32 + bit;
                const uint32_t selfbit = 1u << bit;
                const int ne = (int)nEntries[c];

                // ---- fast pass: any competitor bit anywhere in window? ----
                uint32_t anyComp = 0;
                for (int k = 0; k < ne; ++k) {
                    int wiE = (int)entryWord[c * WPR + k];
                    uint32_t em = entryMask[c * WPR + k];
                    const uint32_t* colp = &win[lr * WPR + wiE];
                    uint32_t orw = 0;
                    #pragma unroll
                    for (int dt = 0; dt < 31; ++dt) {
                        uint32_t h = colp[dt * WPR];
                        if (dt == TR) h &= (wiE == wi) ? ~selfbit : 0xFFFFFFFFu;
                        orw |= h & em;
                    }
                    anyComp |= orw;
                }

                if (anyComp) {
                    // ---- slow path: value comparison on actual hits ----
                    float raw = traces[(long)r * M_CH + c];
                    bool bad = false;
                    for (int k = 0; k < ne && !bad; ++k) {
                        int wiE = (int)entryWord[c * WPR + k];
                        uint32_t em = entryMask[c * WPR + k];
                        const uint32_t* colp = &win[lr * WPR + wiE];
                        #pragma unroll
                        for (int dt = 0; dt < 31; ++dt) {
                            uint32_t h = colp[dt * WPR] & em;
                            if (dt == TR && wiE == wi) h &= ~selfbit;
                            while (h) {
                                int b2 = __ffs(h) - 1;
                                h &= h - 1;
                                float v = traces[(long)(r - TR + dt) * M_CH + wiE * 32 + b2];
                                if (v < raw) bad = true;
                            }
                        }
                    }
                    if (bad) out &= ~selfbit;
                }
            }
        }
        validOut[w] = out;
    }
    int pc = __popc(out);
    #pragma unroll
    for (int off = 32; off; off >>= 1) pc += __shfl_xor(pc, off, 64);
    if ((t & 63) == 0) red[t >> 6] = (uint32_t)pc;
    __syncthreads();
    if (t == 0) chunkCounts[blockIdx.x] = red[0] + red[1] + red[2];
}

// ---------------- K3: exclusive prefix over chunk counts ----------------
__global__ void scan_kernel(const uint32_t* __restrict__ counts, int n,
                            uint32_t* __restrict__ prefix) {
    __shared__ uint32_t s[256];
    int t = threadIdx.x;
    int per = (n + 255) / 256;
    int lo = t * per, hi = min(lo + per, n);
    uint32_t sum = 0;
    for (int i = lo; i < hi; ++i) sum += counts[i];
    s[t] = sum;
    __syncthreads();
    for (int off = 1; off < 256; off <<= 1) {
        uint32_t v = (t >= off) ? s[t - off] : 0;
        __syncthreads();
        s[t] += v;
        __syncthreads();
    }
    uint32_t run = s[t] - sum;
    for (int i = lo; i < hi; ++i) { prefix[i] = run; run += counts[i]; }
    if (t == 255) prefix[n] = run;  // total
}

// ---------------- K4: ordered emit (wave per chunk) + tail fill ----------
__global__ void emit_fill_kernel(const uint32_t* __restrict__ validOut,
                                 const uint32_t* __restrict__ chunkPrefix,
                                 int nchunk, int emitBlocks, int maxdet,
                                 int* __restrict__ times, int* __restrict__ chans) {
    if ((int)blockIdx.x >= emitBlocks) {
        // fill role
        int i = ((int)blockIdx.x - emitBlocks) * 256 + threadIdx.x;
        int total = (int)chunkPrefix[nchunk];
        if (i < maxdet && i >= total) { times[i] = -1; chans[i] = -1; }
        return;
    }
    int wv = threadIdx.x >> 6;
    int lane = threadIdx.x & 63;
    int chunkId = blockIdx.x * 4 + wv;
    if (chunkId >= nchunk) return;

    const uint32_t* wp = validOut + (long)chunkId * BM_WORDS + lane * 3;
    uint32_t b0 = wp[0], b1 = wp[1], b2 = wp[2];
    int local = __popc(b0) + __popc(b1) + __popc(b2);

    int s = local;
    #pragma unroll
    for (int off = 1; off < 64; off <<= 1) {
        int v = __shfl_up(s, off, 64);
        if (lane >= off) s += v;
    }
    int base = (int)chunkPrefix[chunkId] + (s - local);
    int r0 = chunkId * CHUNK_ROWS;

    uint32_t words[3] = { b0, b1, b2 };
    #pragma unroll
    for (int q = 0; q < 3; ++q) {
        uint32_t x = words[q];
        int fbase = (lane * 3 + q) * 32;
        while (x) {
            int b = __ffs(x) - 1;
            x &= x - 1;
            int f = fbase + b;
            int n = f / M_CH;
            int ch = f - n * M_CH;
            if (base < maxdet) {
                times[base] = r0 + n;
                chans[base] = ch;
            }
            base++;
        }
    }
}

extern "C" void kernel_launch(void* const* d_in, const int* in_sizes, int n_in,
                              void* d_out, int out_size, void* d_ws, size_t ws_size,
                              hipStream_t stream) {
    const float* traces = (const float*)d_in[0];
    const float* locs   = (const float*)d_in[1];
    const int M = M_CH;
    const int N = in_sizes[0] / M;            // 150000
    const long nsamp = (long)N * M;           // 57,600,000
    const int maxdet = out_size / 2;          // 100000
    int* times = (int*)d_out;
    int* chans = times + maxdet;

    const long n4     = nsamp / 4;                          // 14,400,000
    const long nwords = nsamp / 32;                         // 1,800,000
    const int  nchunk = (N + CHUNK_ROWS - 1) / CHUNK_ROWS;  // 9375

    char* ws = (char*)d_ws;
    uint32_t* nEntries    = (uint32_t*)(ws + 0);            // 1536
    uint8_t*  entryWord   = (uint8_t*)(ws + 1536);          // 4608   -> 6144
    uint32_t* entryMask   = (uint32_t*)(ws + 6144);         // 18432  -> 24576
    uint32_t* chunkCounts = (uint32_t*)(ws + 24576);        // 37500  -> 62080 (pad)
    uint32_t* chunkPrefix = (uint32_t*)(ws + 62080);        // 37504  -> 99584
    uint32_t* candWords   = (uint32_t*)(ws + 99584);        // 7.2 MB -> 7299584
    uint32_t* validOut    = (uint32_t*)(ws + 7299584);      // 7.2 MB -> 14.5 MB

    // 1024 samples (32 words) per wave; 4 waves per block; +1 block does
    // the neighbor masks (folded former nbr_kernel launch)
    const long nwaves = (nwords + 31) / 32;                 // 56250
    const int  cblocks = (int)((nwaves + 3) / 4);           // 14063
    cand_kernel<<<cblocks + 1, 256, 0, stream>>>(
        traces, locs, n4, nwords, cblocks,
        candWords, nEntries, entryWord, entryMask);

    validate_count_kernel<<<nchunk, BM_WORDS, 0, stream>>>(
        traces, N, nwords, nEntries, entryWord, entryMask, candWords,
        validOut, chunkCounts);

    scan_kernel<<<1, 256, 0, stream>>>(chunkCounts, nchunk, chunkPrefix);

    const int emitBlocks = (nchunk + 3) / 4;                // 2344
    const int fillBlocks = (maxdet + 255) / 256;            // 391
    emit_fill_kernel<<<emitBlocks + fillBlocks, 256, 0, stream>>>(
        validOut, chunkPrefix, nchunk, emitBlocks, maxdet, times, chans);
}